// Round 11
// baseline (490.175 us; speedup 1.0000x reference)
//
#include <hip/hip_runtime.h>

#define NEG_INF -1e30f

typedef __attribute__((ext_vector_type(8))) __bf16 bf16x8;
typedef __attribute__((ext_vector_type(4))) float f32x4;

constexpr int Bb = 16, T = 800, D = 512, V = 5000, L = 100;
constexpr int ROWS = Bb * T;        // 12800
constexpr int S = 2 * L + 1;        // 201
constexpr int SP = 208;             // padded S (13*16)
constexpr int VP = 5120;            // V padded to 128
constexpr int NCB = VP / 128;       // 40 col-blocks (GEMM)
constexpr int NRB = ROWS / 128;     // 100 row-blocks

// float -> bf16 bits, round-to-nearest-even
static __device__ __forceinline__ unsigned short f2bf(float x) {
  union { float f; unsigned u; } v; v.f = x;
  unsigned r = (v.u + 0x7FFFu + ((v.u >> 16) & 1u)) >> 16;
  return (unsigned short)r;
}

// wave_shr:1 (0x138): lane i gets lane i-1; lane 0 (bound_ctrl=0) -> old = NEG_INF
static __device__ __forceinline__ float dpp_shr1_neginf(float x) {
  return __int_as_float(__builtin_amdgcn_update_dpp(
      __float_as_int(NEG_INF), __float_as_int(x), 0x138, 0xF, 0xF, false));
}

// max-subtracted logsumexp helpers (overflow-safe for alpha-magnitude args)
static __device__ __forceinline__ float lse2(float x, float y) {
  float m = fmaxf(x, y);
  return m + __logf(__expf(x - m) + __expf(y - m));
}
static __device__ __forceinline__ float lse3(float x, float y, float z) {
  float m = fmaxf(fmaxf(x, y), z);
  return m + __logf(__expf(x - m) + __expf(y - m) + __expf(z - m));
}
static __device__ __forceinline__ float lse4(float x0, float x1, float x2, float x3) {
  float m = fmaxf(fmaxf(x0, x1), fmaxf(x2, x3));
  return m + __logf(__expf(x0 - m) + __expf(x1 - m) + __expf(x2 - m) + __expf(x3 - m));
}
static __device__ __forceinline__ float lse5(float x0, float x1, float x2, float x3, float x4) {
  float m = fmaxf(fmaxf(fmaxf(x0, x1), fmaxf(x2, x3)), x4);
  return m + __logf(__expf(x0 - m) + __expf(x1 - m) + __expf(x2 - m) +
                    __expf(x3 - m) + __expf(x4 - m));
}

// ---- hs fp32 -> bf16 (row-major [12800][512]) ----
__global__ __launch_bounds__(256) void k_conv_hs(const float* __restrict__ hs,
                                                 unsigned short* __restrict__ A) {
  int i = blockIdx.x * 256 + threadIdx.x;
  float4 f = ((const float4*)hs)[i];
  ushort4 o;
  o.x = f2bf(f.x); o.y = f2bf(f.y); o.z = f2bf(f.z); o.w = f2bf(f.w);
  ((ushort4*)A)[i] = o;
}

// ---- W [512][5000] fp32 -> Wt [5120][512] bf16 (transposed, pad rows zero) ----
__global__ __launch_bounds__(256) void k_transW(const float* __restrict__ W,
                                                unsigned short* __restrict__ Wt) {
  __shared__ float tile[64][65];
  int v0 = blockIdx.x * 64, k0 = blockIdx.y * 64;
  int tl = threadIdx.x & 63, th = threadIdx.x >> 6;
#pragma unroll
  for (int i = 0; i < 16; i++) {
    int k = k0 + th + i * 4;
    int v = v0 + tl;
    tile[th + i * 4][tl] = (v < V) ? W[(size_t)k * V + v] : 0.f;
  }
  __syncthreads();
#pragma unroll
  for (int i = 0; i < 16; i++) {
    int v = v0 + th + i * 4;
    int k = k0 + tl;
    Wt[(size_t)v * D + k] = f2bf(tile[tl][th + i * 4]);
  }
}

// ---- gathered RAW logits at extended labels: glog[b,t,s] = <hs,W[:,ext]> + b[ext] ----
__global__ __launch_bounds__(64) void k_gather(const unsigned short* __restrict__ A,
                                               const unsigned short* __restrict__ Wt,
                                               const float* __restrict__ bias,
                                               const int* __restrict__ labels,
                                               float* __restrict__ glog) {
  int lane = threadIdx.x, q = lane >> 4, c = lane & 15;
  int b = blockIdx.z, t0 = blockIdx.y * 16, s0 = blockIdx.x * 16;
  int s = s0 + c;
  int ev = (s < S && (s & 1)) ? labels[b * L + (s >> 1)] : 0;
  const unsigned short* Brow = Wt + (size_t)ev * D;
  const unsigned short* Arow = A + (size_t)(b * T + t0 + c) * D;
  f32x4 acc = {0.f, 0.f, 0.f, 0.f};
#pragma unroll
  for (int kk = 0; kk < D; kk += 32) {
    bf16x8 a = *(const bf16x8*)(Arow + kk + q * 8);
    bf16x8 bb = *(const bf16x8*)(Brow + kk + q * 8);
    acc = __builtin_amdgcn_mfma_f32_16x16x32_bf16(a, bb, acc, 0, 0, 0);
  }
  float bs = bias[ev];
#pragma unroll
  for (int r = 0; r < 4; r++) {
    int row = b * T + t0 + q * 4 + r;
    glog[(size_t)row * SP + s0 + c] = acc[r] + bs;
  }
}

// ---- FUSED: blocks 0..15 = CTC DP (2-step-composed, one wave);
//             blocks 16..4015 = 128x128 GEMM + softmax partials ----
__global__ __launch_bounds__(256) void k_fused(const unsigned short* __restrict__ A,
                                               const unsigned short* __restrict__ Wt,
                                               const float* __restrict__ bias,
                                               const float* __restrict__ glog,
                                               const int* __restrict__ labels,
                                               const int* __restrict__ hlens,
                                               const int* __restrict__ llens,
                                               float* __restrict__ partM,
                                               float* __restrict__ partS,
                                               float* __restrict__ rawtot) {
  __shared__ unsigned short As[128 * 64];   // GEMM path only
  __shared__ unsigned short Bs[128 * 64];
  __shared__ float redM[2][128];
  __shared__ float redS[2][128];

  int blk = blockIdx.x;
  if (blk < Bb) {
    // ================= DP path: one wave, pair-composed log-semiring =======
    if (threadIdx.x >= 64) return;   // waves 1-3 exit (no barriers in this path)
    int b = blk, l = threadIdx.x;
    int col = 4 * l < SP ? 4 * l : SP - 4;  // lanes >=52 clamp; garbage flows only upward in s
    const float* rp = glog + (size_t)(b * T) * SP + col;
    int i0 = (2 * l < L) ? 2 * l : L - 1;
    int i1 = (2 * l + 1 < L) ? 2 * l + 1 : L - 1;
    int im = (l >= 1) ? 2 * l - 1 : 0; im = im < L ? im : L - 1;
    int im2 = (l >= 1) ? 2 * l - 2 : 0; im2 = im2 < L ? im2 : L - 1;
    int lab0 = labels[b * L + i0];    // ext[4l+1]
    int lab1 = labels[b * L + i1];    // ext[4l+3]
    int labm = labels[b * L + im];    // ext[4l-1]
    int labm2 = labels[b * L + im2];  // ext[4l-3]
    bool sk1 = (l >= 1) && (lab0 != 0) && (lab0 != labm);   // sk[4l+1]
    bool sk3 = (lab1 != 0) && (lab1 != lab0);               // sk[4l+3]
    bool skm1 = (l >= 1) && (labm != 0) && (labm != labm2); // sk[4l-1]
    int hl = hlens[b];

    f32x4 g0 = *(const f32x4*)rp;
    float a0 = (l == 0) ? g0.x : NEG_INF;
    float a1 = (l == 0) ? g0.y : NEG_INF;
    float a2 = NEG_INF, a3 = NEG_INF;

    int nsteps = hl - 1;
    int npairs = nsteps >> 1;
    int remt = nsteps & 1;

    for (int p = 0; p < npairs; p++) {
      int t = 1 + 2 * p;
      f32x4 G1 = *(const f32x4*)(rp + (size_t)t * SP);
      f32x4 G2 = *(const f32x4*)(rp + (size_t)(t + 1) * SP);
      // off-chain: prev-lane g_t neighbor, composed weights V (depend only on G1)
      float gm1 = dpp_shr1_neginf(G1.w);          // g_t[4l-1]
      float V01 = lse2(G1.x, gm1);                // s=4l   k=1
      float V03 = skm1 ? gm1 : NEG_INF;           //        k=3
      float V11 = lse2(G1.y, G1.x);               // s=4l+1 k=1
      float V12 = sk1 ? lse3(G1.y, G1.x, gm1) : G1.x;  //   k=2
      float V13 = sk1 ? gm1 : NEG_INF;            //        k=3
      float V14 = (sk1 && skm1) ? gm1 : NEG_INF;  //        k=4
      float V21 = lse2(G1.z, G1.y);               // s=4l+2 k=1
      float V23 = sk1 ? G1.y : NEG_INF;           //        k=3
      float V31 = lse2(G1.w, G1.z);               // s=4l+3 k=1
      float V32 = sk3 ? lse3(G1.w, G1.z, G1.y) : G1.z; //  k=2
      float V33 = sk3 ? G1.y : NEG_INF;           //        k=3
      float V34 = (sk3 && sk1) ? G1.y : NEG_INF;  //        k=4
      // chain: neighbor alphas, then one 4/5-way lse per state
      float p0 = dpp_shr1_neginf(a0);
      float p1 = dpp_shr1_neginf(a1);
      float p2 = dpp_shr1_neginf(a2);
      float p3 = dpp_shr1_neginf(a3);
      float n0 = lse4(a0 + G1.x, p3 + V01, p2 + gm1, p1 + V03) + G2.x;
      float n1 = lse5(a1 + G1.y, a0 + V11, p3 + V12, p2 + V13, p1 + V14) + G2.y;
      float n2 = lse4(a2 + G1.z, a1 + V21, a0 + G1.y, p3 + V23) + G2.z;
      float n3 = lse5(a3 + G1.w, a2 + V31, a1 + V32, a0 + V33, p3 + V34) + G2.w;
      a0 = n0; a1 = n1; a2 = n2; a3 = n3;
    }
    if (remt) {
      // one trailing single step at t = hl-1 (verified single-step update)
      f32x4 G = *(const f32x4*)(rp + (size_t)(hl - 1) * SP);
      float p3 = dpp_shr1_neginf(a3);
      float s1v = sk1 ? p3 : NEG_INF;
      float n0 = lse2(a0, p3) + G.x;
      float n1 = lse3(a1, a0, s1v) + G.y;
      float n2 = lse2(a2, a1) + G.z;
      float s3v = sk3 ? a1 : NEG_INF;
      float n3 = lse3(a3, a2, s3v) + G.w;
      a0 = n0; a1 = n1; a2 = n2; a3 = n3;
    }

    // extract alpha[2ll], alpha[2ll-1] via shuffles
    int ll = llens[b];
    int s1i = 2 * ll, s2i = 2 * ll - 1;
    int c1 = s1i & 3, c2 = s2i & 3;
    float cand1 = c1 == 0 ? a0 : c1 == 1 ? a1 : c1 == 2 ? a2 : a3;
    float cand2 = c2 == 0 ? a0 : c2 == 1 ? a1 : c2 == 2 ? a2 : a3;
    float v1 = __shfl(cand1, s1i >> 2);
    float v2 = __shfl(cand2, s2i >> 2);
    if (l == 0) rawtot[b] = lse2(v1, v2);
    return;
  }

  // ================= GEMM path (XOR-swizzled LDS, bank-conflict-free) =====
  int gblk = blk - Bb;
  int cb = gblk % NCB, rb = gblk / NCB;
  int tid = threadIdx.x;
  int lane = tid & 63, w = tid >> 6;
  int q = lane >> 4, c = lane & 15;
  int mh = w & 1, nh = w >> 1;
  int row0 = rb * 128, n0 = cb * 128;
  int lr = lane >> 3, lc = lane & 7;
  int oc = (lc ^ lr) * 8;

  f32x4 acc[4][4];
#pragma unroll
  for (int mt = 0; mt < 4; mt++)
#pragma unroll
    for (int nt = 0; nt < 4; nt++) acc[mt][nt] = (f32x4){0.f, 0.f, 0.f, 0.f};

  for (int kk = 0; kk < D; kk += 64) {
#pragma unroll
    for (int j = 0; j < 4; j++) {
      int i = w * 4 + j;
      const unsigned short* ga = A + (size_t)(row0 + i * 8 + lr) * D + kk + oc;
      __builtin_amdgcn_global_load_lds(
          (const __attribute__((address_space(1))) void*)ga,
          (__attribute__((address_space(3))) void*)(As + i * 512), 16, 0, 0);
      const unsigned short* gb = Wt + (size_t)(n0 + i * 8 + lr) * D + kk + oc;
      __builtin_amdgcn_global_load_lds(
          (const __attribute__((address_space(1))) void*)gb,
          (__attribute__((address_space(3))) void*)(Bs + i * 512), 16, 0, 0);
    }
    __syncthreads();
#pragma unroll
    for (int kq = 0; kq < 2; kq++) {
      int o = ((kq * 4 + q) ^ (c & 7)) * 8;
      bf16x8 af[4], bfr[4];
#pragma unroll
      for (int mt = 0; mt < 4; mt++)
        af[mt] = *(const bf16x8*)(As + (mh * 64 + mt * 16 + c) * 64 + o);
#pragma unroll
      for (int nt = 0; nt < 4; nt++)
        bfr[nt] = *(const bf16x8*)(Bs + (nh * 64 + nt * 16 + c) * 64 + o);
#pragma unroll
      for (int mt = 0; mt < 4; mt++)
#pragma unroll
        for (int nt = 0; nt < 4; nt++)
          acc[mt][nt] = __builtin_amdgcn_mfma_f32_16x16x32_bf16(af[mt], bfr[nt], acc[mt][nt], 0, 0, 0);
    }
    __syncthreads();
  }

  int vcb[4]; float bv[4];
#pragma unroll
  for (int nt = 0; nt < 4; nt++) {
    vcb[nt] = n0 + nh * 64 + nt * 16 + c;
    bv[nt] = (vcb[nt] < V) ? bias[vcb[nt]] : 0.f;
  }
#pragma unroll
  for (int mt = 0; mt < 4; mt++) {
#pragma unroll
    for (int r = 0; r < 4; r++) {
      float x[4]; float m = NEG_INF;
#pragma unroll
      for (int nt = 0; nt < 4; nt++) {
        x[nt] = (vcb[nt] < V) ? (acc[mt][nt][r] + bv[nt]) : NEG_INF;
        m = fmaxf(m, x[nt]);
      }
#pragma unroll
      for (int o = 1; o < 16; o <<= 1) m = fmaxf(m, __shfl_xor(m, o));
      float s = 0.f;
#pragma unroll
      for (int nt = 0; nt < 4; nt++) s += __expf(x[nt] - m);
#pragma unroll
      for (int o = 1; o < 16; o <<= 1) s += __shfl_xor(s, o);
      if (c == 0) {
        int rloc = mh * 64 + mt * 16 + q * 4 + r;
        redM[nh][rloc] = m;
        redS[nh][rloc] = s;
      }
    }
  }
  __syncthreads();
  if (tid < 128) {
    float m0 = redM[0][tid], m1 = redM[1][tid];
    float mm = fmaxf(m0, m1);
    float ss = redS[0][tid] * __expf(m0 - mm) + redS[1][tid] * __expf(m1 - mm);
    partM[(size_t)cb * ROWS + row0 + tid] = mm;
    partS[(size_t)cb * ROWS + row0 + tid] = ss;
  }
}

// ---- combine 40 partials -> lse[row] ----
__global__ __launch_bounds__(256) void k_lse(const float* __restrict__ pM,
                                             const float* __restrict__ pS,
                                             float* __restrict__ lse) {
  int row = blockIdx.x * 256 + threadIdx.x;
  float m = pM[row], s = pS[row];
  for (int cb = 1; cb < NCB; cb++) {
    float M2 = pM[(size_t)cb * ROWS + row], S2 = pS[(size_t)cb * ROWS + row];
    float mn = fmaxf(m, M2);
    s = s * __expf(m - mn) + S2 * __expf(M2 - mn);
    m = mn;
  }
  lse[row] = m + __logf(s);
}

// ---- final: tot[b] = rawtot[b] - sum_{t<hl} lse[b,t]; out = mean(-tot) ----
__global__ __launch_bounds__(1024) void k_final(const float* __restrict__ lse,
                                                const float* __restrict__ rawtot,
                                                const int* __restrict__ hlens,
                                                float* __restrict__ out) {
  __shared__ float acc[Bb];
  int w = threadIdx.x >> 6, l = threadIdx.x & 63;  // 16 waves, one per b
  int hl = hlens[w];
  float s = 0.f;
  for (int t = l; t < hl; t += 64) s += lse[w * T + t];
#pragma unroll
  for (int o = 1; o < 64; o <<= 1) s += __shfl_xor(s, o);
  if (l == 0) acc[w] = rawtot[w] - s;
  __syncthreads();
  if (threadIdx.x == 0) {
    float m = 0.f;
    for (int i = 0; i < Bb; i++) m += acc[i];
    out[0] = -m / (float)Bb;
  }
}

extern "C" void kernel_launch(void* const* d_in, const int* in_sizes, int n_in,
                              void* d_out, int out_size, void* d_ws, size_t ws_size,
                              hipStream_t stream) {
  const float* hs    = (const float*)d_in[0];
  const float* W     = (const float*)d_in[1];
  const float* bias  = (const float*)d_in[2];
  const int* hlens   = (const int*)d_in[3];
  const int* labels  = (const int*)d_in[4];
  const int* llens   = (const int*)d_in[5];
  float* out = (float*)d_out;

  char* ws = (char*)d_ws;
  unsigned short* A    = (unsigned short*)(ws);              // 12800*512*2 = 13,107,200
  unsigned short* Wt   = (unsigned short*)(ws + 13107200);   // 5120*512*2  =  5,242,880
  float*          partM= (float*)(ws + 18350080);            // 40*12800*4  =  2,048,000
  float*          partS= (float*)(ws + 20398080);            // 40*12800*4  =  2,048,000
  float*          lse  = (float*)(ws + 22446080);            // 12800*4     =     51,200
  float*          glog = (float*)(ws + 22497280);            // 12800*208*4 = 10,649,600
  float*          rawtot=(float*)(ws + 33146880);            // 16*4

  k_conv_hs<<<ROWS * D / 1024, 256, 0, stream>>>(hs, A);
  k_transW<<<dim3(VP / 64, D / 64), 256, 0, stream>>>(W, Wt);
  k_gather<<<dim3(SP / 16, T / 16, Bb), 64, 0, stream>>>(A, Wt, bias, labels, glog);
  k_fused<<<Bb + NCB * NRB, 256, 0, stream>>>(A, Wt, bias, glog, labels, hlens, llens,
                                              partM, partS, rawtot);
  k_lse<<<ROWS / 256, 256, 0, stream>>>(partM, partS, lse);
  k_final<<<1, 1024, 0, stream>>>(lse, rawtot, hlens, out);

  (void)in_sizes; (void)n_in; (void)out_size; (void)ws_size;
}

// Round 12
// 433.687 us; speedup vs baseline: 1.1303x; 1.1303x over previous
//
#include <hip/hip_runtime.h>

#define NEG_INF -1e30f

typedef __attribute__((ext_vector_type(8))) __bf16 bf16x8;
typedef __attribute__((ext_vector_type(4))) float f32x4;

constexpr int Bb = 16, T = 800, D = 512, V = 5000, L = 100;
constexpr int ROWS = Bb * T;        // 12800
constexpr int S = 2 * L + 1;        // 201
constexpr int SP = 208;             // padded S (13*16)
constexpr int VP = 5120;            // V padded to 128
constexpr int NCB = VP / 128;       // 40 col-blocks (GEMM)
constexpr int NRB = ROWS / 128;     // 100 row-blocks
constexpr int NGB = Bb * 50;        // 800 gather blocks (one per (b, 16-t chunk))
constexpr int CONVB = ROWS * D / 1024;  // 6400 conv blocks

// float -> bf16 bits, round-to-nearest-even
static __device__ __forceinline__ unsigned short f2bf(float x) {
  union { float f; unsigned u; } v; v.f = x;
  unsigned r = (v.u + 0x7FFFu + ((v.u >> 16) & 1u)) >> 16;
  return (unsigned short)r;
}

// wave_shr:1 (0x138): lane i gets lane i-1; lane 0 (bound_ctrl=0) -> old = NEG_INF
static __device__ __forceinline__ float dpp_shr1_neginf(float x) {
  return __int_as_float(__builtin_amdgcn_update_dpp(
      __float_as_int(NEG_INF), __float_as_int(x), 0x138, 0xF, 0xF, false));
}

// ---- PREP: conv_hs (blocks 0..6399) + transW (6400..7039) + flag zeroing ----
__global__ __launch_bounds__(256) void k_prep(const float* __restrict__ hs,
                                              const float* __restrict__ W,
                                              unsigned short* __restrict__ A,
                                              unsigned short* __restrict__ Wt,
                                              int* __restrict__ flags) {
  __shared__ float tile[64][65];
  int blk = blockIdx.x;
  if (blk < CONVB) {
    int i = blk * 256 + threadIdx.x;
    float4 f = ((const float4*)hs)[i];
    ushort4 o;
    o.x = f2bf(f.x); o.y = f2bf(f.y); o.z = f2bf(f.z); o.w = f2bf(f.w);
    ((ushort4*)A)[i] = o;
    return;
  }
  int g = blk - CONVB;                 // 0..639
  if (g == 0) {                        // zero the producer flags
    for (int i = threadIdx.x; i < NGB; i += 256) flags[i] = 0;
  }
  int v0 = (g % (VP / 64)) * 64, k0 = (g / (VP / 64)) * 64;
  int tl = threadIdx.x & 63, th = threadIdx.x >> 6;
#pragma unroll
  for (int i = 0; i < 16; i++) {
    int k = k0 + th + i * 4;
    int v = v0 + tl;
    tile[th + i * 4][tl] = (v < V) ? W[(size_t)k * V + v] : 0.f;
  }
  __syncthreads();
#pragma unroll
  for (int i = 0; i < 16; i++) {
    int v = v0 + th + i * 4;
    int k = k0 + tl;
    Wt[(size_t)v * D + k] = f2bf(tile[tl][th + i * 4]);
  }
}

// ---- MEGA: blocks [0,800)   = gather producers (flagged per (b,chunk));
//            blocks [800,816) = CTC DP consumers (spin-acquire per chunk);
//            blocks [816,4816)= 128x128 GEMM + softmax partials. ----
__global__ __launch_bounds__(256) void k_mega(const unsigned short* __restrict__ A,
                                              const unsigned short* __restrict__ Wt,
                                              const float* __restrict__ bias,
                                              const int* __restrict__ labels,
                                              const int* __restrict__ hlens,
                                              const int* __restrict__ llens,
                                              float* __restrict__ glog,
                                              int* __restrict__ flags,
                                              float* __restrict__ partM,
                                              float* __restrict__ partS,
                                              float* __restrict__ rawtot) {
  __shared__ unsigned short As[128 * 64];   // GEMM path only
  __shared__ unsigned short Bs[128 * 64];
  __shared__ float redM[2][128];
  __shared__ float redS[2][128];

  int blk = blockIdx.x;
  int tid = threadIdx.x;
  int lane = tid & 63, w = tid >> 6;
  int q = lane >> 4, c = lane & 15;

  if (blk < NGB) {
    // ============ GATHER producer: (b, 16-t chunk), 4 waves split 13 s-tiles.
    // Per k-step one shared A-fragment feeds all of this wave's tiles (ILP).
    int b = blk & 15, chk = blk >> 4;
    int t0 = chk * 16;
    int bT = b * T, bL = b * L;
    int st0 = (w == 0) ? 0 : 4 + (w - 1) * 3;   // tiles: 4,3,3,3
    int nst = (w == 0) ? 4 : 3;

    int evs[4]; float bvs[4];
#pragma unroll
    for (int j = 0; j < 4; j++) {
      int st = st0 + (j < nst ? j : nst - 1);
      int s = st * 16 + c;
      evs[j] = (s < S && (s & 1)) ? labels[bL + (s >> 1)] : 0;
      bvs[j] = bias[evs[j]];
    }
    const unsigned short* Arow = A + (size_t)(bT + t0 + c) * D;
    f32x4 acc[4];
#pragma unroll
    for (int j = 0; j < 4; j++) acc[j] = (f32x4){0.f, 0.f, 0.f, 0.f};
    for (int kk = 0; kk < D; kk += 32) {
      bf16x8 aa = *(const bf16x8*)(Arow + kk + q * 8);
#pragma unroll
      for (int j = 0; j < 4; j++) {
        bf16x8 bb = *(const bf16x8*)(Wt + (size_t)evs[j] * D + kk + q * 8);
        acc[j] = __builtin_amdgcn_mfma_f32_16x16x32_bf16(aa, bb, acc[j], 0, 0, 0);
      }
    }
#pragma unroll
    for (int j = 0; j < 4; j++) {
      if (j >= nst) break;
      int st = st0 + j;
#pragma unroll
      for (int r = 0; r < 4; r++)
        glog[(size_t)(bT + t0 + q * 4 + r) * SP + st * 16 + c] = acc[j][r] + bvs[j];
    }
    __threadfence();       // make glog writes device-visible before the flag
    __syncthreads();       // all waves done
    if (tid == 0) atomicExch(&flags[b * 50 + chk], 1);
    return;
  }

  if (blk < NGB + Bb) {
    // ============ DP consumer: one wave, log domain, DPP neighbor ==========
    if (tid >= 64) return;   // waves 1-3 exit (no barriers in this path)
    int b = blk - NGB, l = tid;
    int col = 4 * l < SP ? 4 * l : SP - 4;  // lanes >=52 clamp; garbage flows only upward in s
    const float* rp = glog + (size_t)(b * T) * SP + col;
    int i0 = (2 * l < L) ? 2 * l : L - 1;
    int i1 = (2 * l + 1 < L) ? 2 * l + 1 : L - 1;
    int im = (l >= 1) ? 2 * l - 1 : 0; im = im < L ? im : L - 1;
    int lab0 = labels[b * L + i0];
    int lab1 = labels[b * L + i1];
    int labm = labels[b * L + im];
    bool sk1 = (l >= 1) && (lab0 != 0) && (lab0 != labm);
    bool sk3 = (lab1 != 0) && (lab1 != lab0);
    int hl = hlens[b];

    float a0 = NEG_INF, a1 = NEG_INF, a2 = NEG_INF, a3 = NEG_INF;

#define DP_STEP(G) {                                                          \
    float p3 = dpp_shr1_neginf(a3);              /* alpha[4l-1] */            \
    float s1 = sk1 ? p3 : NEG_INF;                                            \
    float m0 = fmaxf(a0, p3);                                                 \
    float n0 = m0 + __logf(__expf(a0 - m0) + __expf(p3 - m0)) + (G).x;        \
    float m1 = fmaxf(fmaxf(a1, a0), s1);                                      \
    float n1 = m1 + __logf(__expf(a1 - m1) + __expf(a0 - m1) + __expf(s1 - m1)) + (G).y; \
    float m2 = fmaxf(a2, a1);                                                 \
    float n2 = m2 + __logf(__expf(a2 - m2) + __expf(a1 - m2)) + (G).z;        \
    float s3 = sk3 ? a1 : NEG_INF;                                            \
    float m3 = fmaxf(fmaxf(a3, a2), s3);                                      \
    float n3 = m3 + __logf(__expf(a3 - m3) + __expf(a2 - m3) + __expf(s3 - m3)) + (G).w; \
    a0 = n0; a1 = n1; a2 = n2; a3 = n3; }

    int nch = (hl + 15) >> 4;           // chunks of rows 0..hl-1
    for (int ch = 0; ch < nch; ch++) {
      if (l == 0) {
        while (atomicAdd(&flags[b * 50 + ch], 0) == 0) __builtin_amdgcn_s_sleep(8);
      }
      __threadfence();                  // acquire side
      int tlo = ch * 16;
      int thi = tlo + 16 < hl ? tlo + 16 : hl;
      if (ch == 0) {
        f32x4 g0 = *(const f32x4*)rp;
        a0 = (l == 0) ? g0.x : NEG_INF;
        a1 = (l == 0) ? g0.y : NEG_INF;
        a2 = NEG_INF; a3 = NEG_INF;
        tlo = 1;
      }
      for (int t = tlo; t < thi; t++) {
        f32x4 G = *(const f32x4*)(rp + (size_t)t * SP);
        DP_STEP(G)
      }
    }
#undef DP_STEP

    // extract alpha[2ll], alpha[2ll-1] via shuffles
    int ll = llens[b];
    int s1i = 2 * ll, s2i = 2 * ll - 1;
    int c1 = s1i & 3, c2 = s2i & 3;
    float cand1 = c1 == 0 ? a0 : c1 == 1 ? a1 : c1 == 2 ? a2 : a3;
    float cand2 = c2 == 0 ? a0 : c2 == 1 ? a1 : c2 == 2 ? a2 : a3;
    float v1 = __shfl(cand1, s1i >> 2);
    float v2 = __shfl(cand2, s2i >> 2);
    if (l == 0) {
      float m = fmaxf(v1, v2);
      rawtot[b] = m + __logf(__expf(v1 - m) + __expf(v2 - m));
    }
    return;
  }

  // ================= GEMM path (XOR-swizzled LDS, bank-conflict-free) =====
  int gblk = blk - NGB - Bb;
  int cb = gblk % NCB, rb = gblk / NCB;
  int mh = w & 1, nh = w >> 1;
  int row0 = rb * 128, n0 = cb * 128;
  int lr = lane >> 3, lc = lane & 7;
  int oc = (lc ^ lr) * 8;

  f32x4 acc[4][4];
#pragma unroll
  for (int mt = 0; mt < 4; mt++)
#pragma unroll
    for (int nt = 0; nt < 4; nt++) acc[mt][nt] = (f32x4){0.f, 0.f, 0.f, 0.f};

  for (int kk = 0; kk < D; kk += 64) {
#pragma unroll
    for (int j = 0; j < 4; j++) {
      int i = w * 4 + j;
      const unsigned short* ga = A + (size_t)(row0 + i * 8 + lr) * D + kk + oc;
      __builtin_amdgcn_global_load_lds(
          (const __attribute__((address_space(1))) void*)ga,
          (__attribute__((address_space(3))) void*)(As + i * 512), 16, 0, 0);
      const unsigned short* gb = Wt + (size_t)(n0 + i * 8 + lr) * D + kk + oc;
      __builtin_amdgcn_global_load_lds(
          (const __attribute__((address_space(1))) void*)gb,
          (__attribute__((address_space(3))) void*)(Bs + i * 512), 16, 0, 0);
    }
    __syncthreads();
#pragma unroll
    for (int kq = 0; kq < 2; kq++) {
      int o = ((kq * 4 + q) ^ (c & 7)) * 8;
      bf16x8 af[4], bfr[4];
#pragma unroll
      for (int mt = 0; mt < 4; mt++)
        af[mt] = *(const bf16x8*)(As + (mh * 64 + mt * 16 + c) * 64 + o);
#pragma unroll
      for (int nt = 0; nt < 4; nt++)
        bfr[nt] = *(const bf16x8*)(Bs + (nh * 64 + nt * 16 + c) * 64 + o);
#pragma unroll
      for (int mt = 0; mt < 4; mt++)
#pragma unroll
        for (int nt = 0; nt < 4; nt++)
          acc[mt][nt] = __builtin_amdgcn_mfma_f32_16x16x32_bf16(af[mt], bfr[nt], acc[mt][nt], 0, 0, 0);
    }
    __syncthreads();
  }

  int vcb[4]; float bv[4];
#pragma unroll
  for (int nt = 0; nt < 4; nt++) {
    vcb[nt] = n0 + nh * 64 + nt * 16 + c;
    bv[nt] = (vcb[nt] < V) ? bias[vcb[nt]] : 0.f;
  }
#pragma unroll
  for (int mt = 0; mt < 4; mt++) {
#pragma unroll
    for (int r = 0; r < 4; r++) {
      float x[4]; float m = NEG_INF;
#pragma unroll
      for (int nt = 0; nt < 4; nt++) {
        x[nt] = (vcb[nt] < V) ? (acc[mt][nt][r] + bv[nt]) : NEG_INF;
        m = fmaxf(m, x[nt]);
      }
#pragma unroll
      for (int o = 1; o < 16; o <<= 1) m = fmaxf(m, __shfl_xor(m, o));
      float s = 0.f;
#pragma unroll
      for (int nt = 0; nt < 4; nt++) s += __expf(x[nt] - m);
#pragma unroll
      for (int o = 1; o < 16; o <<= 1) s += __shfl_xor(s, o);
      if (c == 0) {
        int rloc = mh * 64 + mt * 16 + q * 4 + r;
        redM[nh][rloc] = m;
        redS[nh][rloc] = s;
      }
    }
  }
  __syncthreads();
  if (tid < 128) {
    float m0 = redM[0][tid], m1 = redM[1][tid];
    float mm = fmaxf(m0, m1);
    float ss = redS[0][tid] * __expf(m0 - mm) + redS[1][tid] * __expf(m1 - mm);
    partM[(size_t)cb * ROWS + row0 + tid] = mm;
    partS[(size_t)cb * ROWS + row0 + tid] = ss;
  }
}

// ---- combine 40 partials -> lse[row] ----
__global__ __launch_bounds__(256) void k_lse(const float* __restrict__ pM,
                                             const float* __restrict__ pS,
                                             float* __restrict__ lse) {
  int row = blockIdx.x * 256 + threadIdx.x;
  float m = pM[row], s = pS[row];
  for (int cb = 1; cb < NCB; cb++) {
    float M2 = pM[(size_t)cb * ROWS + row], S2 = pS[(size_t)cb * ROWS + row];
    float mn = fmaxf(m, M2);
    s = s * __expf(m - mn) + S2 * __expf(M2 - mn);
    m = mn;
  }
  lse[row] = m + __logf(s);
}

// ---- final: tot[b] = rawtot[b] - sum_{t<hl} lse[b,t]; out = mean(-tot) ----
__global__ __launch_bounds__(1024) void k_final(const float* __restrict__ lse,
                                                const float* __restrict__ rawtot,
                                                const int* __restrict__ hlens,
                                                float* __restrict__ out) {
  __shared__ float acc[Bb];
  int w = threadIdx.x >> 6, l = threadIdx.x & 63;  // 16 waves, one per b
  int hl = hlens[w];
  float s = 0.f;
  for (int t = l; t < hl; t += 64) s += lse[w * T + t];
#pragma unroll
  for (int o = 1; o < 64; o <<= 1) s += __shfl_xor(s, o);
  if (l == 0) acc[w] = rawtot[w] - s;
  __syncthreads();
  if (threadIdx.x == 0) {
    float m = 0.f;
    for (int i = 0; i < Bb; i++) m += acc[i];
    out[0] = -m / (float)Bb;
  }
}

extern "C" void kernel_launch(void* const* d_in, const int* in_sizes, int n_in,
                              void* d_out, int out_size, void* d_ws, size_t ws_size,
                              hipStream_t stream) {
  const float* hs    = (const float*)d_in[0];
  const float* W     = (const float*)d_in[1];
  const float* bias  = (const float*)d_in[2];
  const int* hlens   = (const int*)d_in[3];
  const int* labels  = (const int*)d_in[4];
  const int* llens   = (const int*)d_in[5];
  float* out = (float*)d_out;

  char* ws = (char*)d_ws;
  unsigned short* A    = (unsigned short*)(ws);              // 12800*512*2 = 13,107,200
  unsigned short* Wt   = (unsigned short*)(ws + 13107200);   // 5120*512*2  =  5,242,880
  float*          partM= (float*)(ws + 18350080);            // 40*12800*4  =  2,048,000
  float*          partS= (float*)(ws + 20398080);            // 40*12800*4  =  2,048,000
  float*          lse  = (float*)(ws + 22446080);            // 12800*4     =     51,200
  float*          glog = (float*)(ws + 22497280);            // 12800*208*4 = 10,649,600
  float*          rawtot=(float*)(ws + 33146880);            // 16*4 (pad to 64)
  int*            flags= (int*)(ws + 33146944);              // 800*4

  k_prep<<<CONVB + (VP / 64) * (D / 64), 256, 0, stream>>>(hs, W, A, Wt, flags);
  k_mega<<<NGB + Bb + NCB * NRB, 256, 0, stream>>>(A, Wt, bias, labels, hlens, llens,
                                                   glog, flags, partM, partS, rawtot);
  k_lse<<<ROWS / 256, 256, 0, stream>>>(partM, partS, lse);
  k_final<<<1, 1024, 0, stream>>>(lse, rawtot, hlens, out);

  (void)in_sizes; (void)n_in; (void)out_size; (void)ws_size;
}

// Round 13
// 342.023 us; speedup vs baseline: 1.4332x; 1.2680x over previous
//
#include <hip/hip_runtime.h>

#define NEG_INF -1e30f

typedef __attribute__((ext_vector_type(8))) __bf16 bf16x8;
typedef __attribute__((ext_vector_type(4))) float f32x4;

constexpr int Bb = 16, T = 800, D = 512, V = 5000, L = 100;
constexpr int ROWS = Bb * T;        // 12800
constexpr int S = 2 * L + 1;        // 201
constexpr int SP = 208;             // padded S (13*16)
constexpr int VP = 5120;            // V padded to 128
constexpr int NCB = VP / 128;       // 40 col-blocks (GEMM)
constexpr int NRB = ROWS / 128;     // 100 row-blocks
constexpr int NGB = Bb * 50;        // 800 gather blocks (one per (b, 16-t chunk))
constexpr int CONVB = ROWS * D / 1024;  // 6400 conv blocks

// float -> bf16 bits, round-to-nearest-even
static __device__ __forceinline__ unsigned short f2bf(float x) {
  union { float f; unsigned u; } v; v.f = x;
  unsigned r = (v.u + 0x7FFFu + ((v.u >> 16) & 1u)) >> 16;
  return (unsigned short)r;
}

// wave_shr:1 (0x138): lane i gets lane i-1; lane 0 (bound_ctrl=0) -> old = NEG_INF
static __device__ __forceinline__ float dpp_shr1_neginf(float x) {
  return __int_as_float(__builtin_amdgcn_update_dpp(
      __float_as_int(NEG_INF), __float_as_int(x), 0x138, 0xF, 0xF, false));
}

// ---- PREP: conv_hs (blocks 0..6399) + transW (6400..7039) ----
__global__ __launch_bounds__(256) void k_prep(const float* __restrict__ hs,
                                              const float* __restrict__ W,
                                              unsigned short* __restrict__ A,
                                              unsigned short* __restrict__ Wt) {
  __shared__ float tile[64][65];
  int blk = blockIdx.x;
  if (blk < CONVB) {
    int i = blk * 256 + threadIdx.x;
    float4 f = ((const float4*)hs)[i];
    ushort4 o;
    o.x = f2bf(f.x); o.y = f2bf(f.y); o.z = f2bf(f.z); o.w = f2bf(f.w);
    ((ushort4*)A)[i] = o;
    return;
  }
  int g = blk - CONVB;                 // 0..639
  int v0 = (g % (VP / 64)) * 64, k0 = (g / (VP / 64)) * 64;
  int tl = threadIdx.x & 63, th = threadIdx.x >> 6;
#pragma unroll
  for (int i = 0; i < 16; i++) {
    int k = k0 + th + i * 4;
    int v = v0 + tl;
    tile[th + i * 4][tl] = (v < V) ? W[(size_t)k * V + v] : 0.f;
  }
  __syncthreads();
#pragma unroll
  for (int i = 0; i < 16; i++) {
    int v = v0 + th + i * 4;
    int k = k0 + tl;
    Wt[(size_t)v * D + k] = f2bf(tile[tl][th + i * 4]);
  }
}

// ---- gathered RAW logits (restructured): one block per (b, 16-t chunk),
//      4 waves split the 13 s-tiles (4,3,3,3); per k-step one A-fragment
//      feeds all of a wave's tiles -> 4-way interleaved MFMA chains (ILP) ----
__global__ __launch_bounds__(256) void k_gather(const unsigned short* __restrict__ A,
                                                const unsigned short* __restrict__ Wt,
                                                const float* __restrict__ bias,
                                                const int* __restrict__ labels,
                                                float* __restrict__ glog) {
  int tid = threadIdx.x;
  int lane = tid & 63, w = tid >> 6;
  int q = lane >> 4, c = lane & 15;
  int b = blockIdx.x & 15, chk = blockIdx.x >> 4;
  int t0 = chk * 16;
  int bT = b * T, bL = b * L;
  int st0 = (w == 0) ? 0 : 4 + (w - 1) * 3;   // tiles: 4,3,3,3
  int nst = (w == 0) ? 4 : 3;

  int evs[4]; float bvs[4];
#pragma unroll
  for (int j = 0; j < 4; j++) {
    int st = st0 + (j < nst ? j : nst - 1);
    int s = st * 16 + c;
    evs[j] = (s < S && (s & 1)) ? labels[bL + (s >> 1)] : 0;
    bvs[j] = bias[evs[j]];
  }
  const unsigned short* Arow = A + (size_t)(bT + t0 + c) * D;
  f32x4 acc[4];
#pragma unroll
  for (int j = 0; j < 4; j++) acc[j] = (f32x4){0.f, 0.f, 0.f, 0.f};
  for (int kk = 0; kk < D; kk += 32) {
    bf16x8 aa = *(const bf16x8*)(Arow + kk + q * 8);
#pragma unroll
    for (int j = 0; j < 4; j++) {
      bf16x8 bb = *(const bf16x8*)(Wt + (size_t)evs[j] * D + kk + q * 8);
      acc[j] = __builtin_amdgcn_mfma_f32_16x16x32_bf16(aa, bb, acc[j], 0, 0, 0);
    }
  }
#pragma unroll
  for (int j = 0; j < 4; j++) {
    if (j >= nst) break;
    int st = st0 + j;
#pragma unroll
    for (int r = 0; r < 4; r++)
      glog[(size_t)(bT + t0 + q * 4 + r) * SP + st * 16 + c] = acc[j][r] + bvs[j];
  }
}

// ---- FUSED: blocks 0..15 = CTC DP on raw logits (16 CUs);
//             blocks 16..4015 = 128x128 GEMM + softmax partials ----
__global__ __launch_bounds__(256) void k_fused(const unsigned short* __restrict__ A,
                                               const unsigned short* __restrict__ Wt,
                                               const float* __restrict__ bias,
                                               const float* __restrict__ glog,
                                               const int* __restrict__ labels,
                                               const int* __restrict__ hlens,
                                               const int* __restrict__ llens,
                                               float* __restrict__ partM,
                                               float* __restrict__ partS,
                                               float* __restrict__ rawtot) {
  __shared__ unsigned short As[128 * 64];   // GEMM path only
  __shared__ unsigned short Bs[128 * 64];
  __shared__ float redM[2][128];
  __shared__ float redS[2][128];

  int blk = blockIdx.x;
  if (blk < Bb) {
    // ================= DP path: one wave, log domain, DPP neighbor ========
    if (threadIdx.x >= 64) return;   // waves 1-3 exit (no barriers in this path)
    int b = blk, l = threadIdx.x;
    int col = 4 * l < SP ? 4 * l : SP - 4;  // lanes >=52 clamp; garbage flows only upward in s
    const float* rp = glog + (size_t)(b * T) * SP + col;
    int i0 = (2 * l < L) ? 2 * l : L - 1;
    int i1 = (2 * l + 1 < L) ? 2 * l + 1 : L - 1;
    int im = (l >= 1) ? 2 * l - 1 : 0; im = im < L ? im : L - 1;
    int lab0 = labels[b * L + i0];
    int lab1 = labels[b * L + i1];
    int labm = labels[b * L + im];
    bool sk1 = (l >= 1) && (lab0 != 0) && (lab0 != labm);
    bool sk3 = (lab1 != 0) && (lab1 != lab0);
    int hl = hlens[b];

    f32x4 g0 = *(const f32x4*)rp;
    float a0 = (l == 0) ? g0.x : NEG_INF;
    float a1 = (l == 0) ? g0.y : NEG_INF;
    float a2 = NEG_INF, a3 = NEG_INF;

#define DP_STEP(G) {                                                          \
    float p3 = dpp_shr1_neginf(a3);              /* alpha[4l-1] */            \
    float s1 = sk1 ? p3 : NEG_INF;                                            \
    float m0 = fmaxf(a0, p3);                                                 \
    float n0 = m0 + __logf(__expf(a0 - m0) + __expf(p3 - m0)) + (G).x;        \
    float m1 = fmaxf(fmaxf(a1, a0), s1);                                      \
    float n1 = m1 + __logf(__expf(a1 - m1) + __expf(a0 - m1) + __expf(s1 - m1)) + (G).y; \
    float m2 = fmaxf(a2, a1);                                                 \
    float n2 = m2 + __logf(__expf(a2 - m2) + __expf(a1 - m2)) + (G).z;        \
    float s3 = sk3 ? a1 : NEG_INF;                                            \
    float m3 = fmaxf(fmaxf(a3, a2), s3);                                      \
    float n3 = m3 + __logf(__expf(a3 - m3) + __expf(a2 - m3) + __expf(s3 - m3)) + (G).w; \
    a0 = n0; a1 = n1; a2 = n2; a3 = n3; }

    for (int t = 1; t < hl; t++) {
      f32x4 G = *(const f32x4*)(rp + (size_t)t * SP);
      DP_STEP(G)
    }
#undef DP_STEP

    // extract alpha[2ll], alpha[2ll-1] via shuffles
    int ll = llens[b];
    int s1i = 2 * ll, s2i = 2 * ll - 1;
    int c1 = s1i & 3, c2 = s2i & 3;
    float cand1 = c1 == 0 ? a0 : c1 == 1 ? a1 : c1 == 2 ? a2 : a3;
    float cand2 = c2 == 0 ? a0 : c2 == 1 ? a1 : c2 == 2 ? a2 : a3;
    float v1 = __shfl(cand1, s1i >> 2);
    float v2 = __shfl(cand2, s2i >> 2);
    if (l == 0) {
      float m = fmaxf(v1, v2);
      rawtot[b] = m + __logf(__expf(v1 - m) + __expf(v2 - m));
    }
    return;
  }

  // ================= GEMM path (XOR-swizzled LDS, bank-conflict-free) =====
  int gblk = blk - Bb;
  int cb = gblk % NCB, rb = gblk / NCB;
  int tid = threadIdx.x;
  int lane = tid & 63, w = tid >> 6;
  int q = lane >> 4, c = lane & 15;
  int mh = w & 1, nh = w >> 1;
  int row0 = rb * 128, n0 = cb * 128;
  int lr = lane >> 3, lc = lane & 7;
  int oc = (lc ^ lr) * 8;

  f32x4 acc[4][4];
#pragma unroll
  for (int mt = 0; mt < 4; mt++)
#pragma unroll
    for (int nt = 0; nt < 4; nt++) acc[mt][nt] = (f32x4){0.f, 0.f, 0.f, 0.f};

  for (int kk = 0; kk < D; kk += 64) {
#pragma unroll
    for (int j = 0; j < 4; j++) {
      int i = w * 4 + j;
      const unsigned short* ga = A + (size_t)(row0 + i * 8 + lr) * D + kk + oc;
      __builtin_amdgcn_global_load_lds(
          (const __attribute__((address_space(1))) void*)ga,
          (__attribute__((address_space(3))) void*)(As + i * 512), 16, 0, 0);
      const unsigned short* gb = Wt + (size_t)(n0 + i * 8 + lr) * D + kk + oc;
      __builtin_amdgcn_global_load_lds(
          (const __attribute__((address_space(1))) void*)gb,
          (__attribute__((address_space(3))) void*)(Bs + i * 512), 16, 0, 0);
    }
    __syncthreads();
#pragma unroll
    for (int kq = 0; kq < 2; kq++) {
      int o = ((kq * 4 + q) ^ (c & 7)) * 8;
      bf16x8 af[4], bfr[4];
#pragma unroll
      for (int mt = 0; mt < 4; mt++)
        af[mt] = *(const bf16x8*)(As + (mh * 64 + mt * 16 + c) * 64 + o);
#pragma unroll
      for (int nt = 0; nt < 4; nt++)
        bfr[nt] = *(const bf16x8*)(Bs + (nh * 64 + nt * 16 + c) * 64 + o);
#pragma unroll
      for (int mt = 0; mt < 4; mt++)
#pragma unroll
        for (int nt = 0; nt < 4; nt++)
          acc[mt][nt] = __builtin_amdgcn_mfma_f32_16x16x32_bf16(af[mt], bfr[nt], acc[mt][nt], 0, 0, 0);
    }
    __syncthreads();
  }

  int vcb[4]; float bv[4];
#pragma unroll
  for (int nt = 0; nt < 4; nt++) {
    vcb[nt] = n0 + nh * 64 + nt * 16 + c;
    bv[nt] = (vcb[nt] < V) ? bias[vcb[nt]] : 0.f;
  }
#pragma unroll
  for (int mt = 0; mt < 4; mt++) {
#pragma unroll
    for (int r = 0; r < 4; r++) {
      float x[4]; float m = NEG_INF;
#pragma unroll
      for (int nt = 0; nt < 4; nt++) {
        x[nt] = (vcb[nt] < V) ? (acc[mt][nt][r] + bv[nt]) : NEG_INF;
        m = fmaxf(m, x[nt]);
      }
#pragma unroll
      for (int o = 1; o < 16; o <<= 1) m = fmaxf(m, __shfl_xor(m, o));
      float s = 0.f;
#pragma unroll
      for (int nt = 0; nt < 4; nt++) s += __expf(x[nt] - m);
#pragma unroll
      for (int o = 1; o < 16; o <<= 1) s += __shfl_xor(s, o);
      if (c == 0) {
        int rloc = mh * 64 + mt * 16 + q * 4 + r;
        redM[nh][rloc] = m;
        redS[nh][rloc] = s;
      }
    }
  }
  __syncthreads();
  if (tid < 128) {
    float m0 = redM[0][tid], m1 = redM[1][tid];
    float mm = fmaxf(m0, m1);
    float ss = redS[0][tid] * __expf(m0 - mm) + redS[1][tid] * __expf(m1 - mm);
    partM[(size_t)cb * ROWS + row0 + tid] = mm;
    partS[(size_t)cb * ROWS + row0 + tid] = ss;
  }
}

// ---- combine 40 partials -> lse[row] ----
__global__ __launch_bounds__(256) void k_lse(const float* __restrict__ pM,
                                             const float* __restrict__ pS,
                                             float* __restrict__ lse) {
  int row = blockIdx.x * 256 + threadIdx.x;
  float m = pM[row], s = pS[row];
  for (int cb = 1; cb < NCB; cb++) {
    float M2 = pM[(size_t)cb * ROWS + row], S2 = pS[(size_t)cb * ROWS + row];
    float mn = fmaxf(m, M2);
    s = s * __expf(m - mn) + S2 * __expf(M2 - mn);
    m = mn;
  }
  lse[row] = m + __logf(s);
}

// ---- final: tot[b] = rawtot[b] - sum_{t<hl} lse[b,t]; out = mean(-tot) ----
__global__ __launch_bounds__(1024) void k_final(const float* __restrict__ lse,
                                                const float* __restrict__ rawtot,
                                                const int* __restrict__ hlens,
                                                float* __restrict__ out) {
  __shared__ float acc[Bb];
  int w = threadIdx.x >> 6, l = threadIdx.x & 63;  // 16 waves, one per b
  int hl = hlens[w];
  float s = 0.f;
  for (int t = l; t < hl; t += 64) s += lse[w * T + t];
#pragma unroll
  for (int o = 1; o < 64; o <<= 1) s += __shfl_xor(s, o);
  if (l == 0) acc[w] = rawtot[w] - s;
  __syncthreads();
  if (threadIdx.x == 0) {
    float m = 0.f;
    for (int i = 0; i < Bb; i++) m += acc[i];
    out[0] = -m / (float)Bb;
  }
}

extern "C" void kernel_launch(void* const* d_in, const int* in_sizes, int n_in,
                              void* d_out, int out_size, void* d_ws, size_t ws_size,
                              hipStream_t stream) {
  const float* hs    = (const float*)d_in[0];
  const float* W     = (const float*)d_in[1];
  const float* bias  = (const float*)d_in[2];
  const int* hlens   = (const int*)d_in[3];
  const int* labels  = (const int*)d_in[4];
  const int* llens   = (const int*)d_in[5];
  float* out = (float*)d_out;

  char* ws = (char*)d_ws;
  unsigned short* A    = (unsigned short*)(ws);              // 12800*512*2 = 13,107,200
  unsigned short* Wt   = (unsigned short*)(ws + 13107200);   // 5120*512*2  =  5,242,880
  float*          partM= (float*)(ws + 18350080);            // 40*12800*4  =  2,048,000
  float*          partS= (float*)(ws + 20398080);            // 40*12800*4  =  2,048,000
  float*          lse  = (float*)(ws + 22446080);            // 12800*4     =     51,200
  float*          glog = (float*)(ws + 22497280);            // 12800*208*4 = 10,649,600
  float*          rawtot=(float*)(ws + 33146880);            // 16*4

  k_prep<<<CONVB + (VP / 64) * (D / 64), 256, 0, stream>>>(hs, W, A, Wt);
  k_gather<<<NGB, 256, 0, stream>>>(A, Wt, bias, labels, glog);
  k_fused<<<Bb + NCB * NRB, 256, 0, stream>>>(A, Wt, bias, glog, labels, hlens, llens,
                                              partM, partS, rawtot);
  k_lse<<<ROWS / 256, 256, 0, stream>>>(partM, partS, lse);
  k_final<<<1, 1024, 0, stream>>>(lse, rawtot, hlens, out);

  (void)in_sizes; (void)n_in; (void)out_size; (void)ws_size;
}